// Round 17
// baseline (1855.550 us; speedup 1.0000x reference)
//
#include <hip/hip_runtime.h>

#define B 64
#define T 256
#define H 512
#define G4 2048
#define D0 128
#define NL 6
#define NBLK_P 192            // 6 layers x 32 col-groups
#define SKEW 2                // layer skew: inter-layer slack = 1 step
#define GTOT (T + SKEW * (NL - 1))   // 266 global steps
#define FSTRIDE 16            // u32 stride between per-block flags (64B)
#define HSTRA 584             // h_sA row stride f16 (1168B == 16 mod 128)
#define HSTRB 520             // h_sB row stride f16 (1040B == 16 mod 128)
#define GSTR 36               // g_par row stride f32

typedef float f32x4 __attribute__((ext_vector_type(4)));
typedef float f32x16 __attribute__((ext_vector_type(16)));
typedef _Float16 h16x8 __attribute__((ext_vector_type(8)));

// ===========================================================================
// lstm_pipe v9 — r16 (skew-2, local flags, full-depth L2-cached ring) with
// PER-PRODUCER STREAMING STAGE:
//  * 1024 threads = 32 groups x 32. Group p polls ONLY producer p's flag,
//    then immediately copies p's 2KB slice (cols [16p,16p+16) x 64 batch)
//    into LDS. 31 slices stream in under the straggler's latency; after the
//    last flag only its own 2KB copy + MFMA remain on the critical path.
//    (r16 waited for max(32 flags) and THEN staged all 64KB serially.)
//  * Same structure on phase A (l-1 edge, threshold g-1).
//  * Freshness per slice: producer p's data stores drain (vmcnt via its
//    pre-flag syncthreads) BEFORE its flag store; consumer first-touch of
//    the never-reused slot misses L2 and fills from L3 -> fresh. Identical
//    argument to r16, just per-producer granularity (r16 verified bit-exact).
//  * Syncs/step: 6 -> 4. Math/accum order bit-identical to r12-r16:
//    absmax must be exactly 0.0001220703.
//  * Full-depth ring (96MB) — ws size empirically confirmed by r16. No WAR.
// ===========================================================================
__global__ void __launch_bounds__(1024, 4) lstm_pipe(
    const float* __restrict__ x,
    const float* __restrict__ Wih0, const float* __restrict__ WihR,
    const float* __restrict__ Whh,
    const float* __restrict__ bih, const float* __restrict__ bhh,
    unsigned short* __restrict__ ring, float* __restrict__ h5,
    unsigned* __restrict__ flags)
{
  __shared__ unsigned short h_sA[64 * HSTRA];   // 74752 B (g_par aliases)
  __shared__ unsigned short h_sB[64 * HSTRB];   // 66560 B
  float* const g_par = (float*)h_sA;

  const int tid  = threadIdx.x;
  const int lane = tid & 63;
  const int wl   = __builtin_amdgcn_readfirstlane(tid >> 6);
  const int ks   = wl & 3;
  const int rt   = (wl >> 2) >> 1;
  const int bt   = (wl >> 2) & 1;
  const int blk  = (int)blockIdx.x;
  const int l    = blk >> 5;
  const int jb   = blk & 31;
  const int j0   = jb * 16;
  const int Kin  = (l == 0) ? D0 : H;
  const int KA4  = Kin >> 2;                // per-ks k width, phase A
  const int FA   = KA4 >> 4;                // phase-A frags: 2 or 8

  const float* WihA = (l == 0) ? Wih0 : (WihR + (size_t)(l - 1) * G4 * H);
  const float* WhhA = Whh + (size_t)l * G4 * H;

  // ---- one-time: W -> A-fragments in registers (f16; r12-verified map) ----
  h16x8 aA[8], aB[8];
  {
    const int ri   = rt * 32 + (lane & 31);
    const int grow = (ri >> 4) * H + j0 + (ri & 15);
    const float* wihRow = WihA + (size_t)grow * Kin;
    const float* whhRow = WhhA + (size_t)grow * H;
    const int klane = (lane >> 5) * 8;
#pragma unroll
    for (int m = 0; m < 8; ++m) {
      h16x8 fa = {};
      if (m < FA) {
        const float* src = wihRow + ks * KA4 + m * 16 + klane;
        f32x4 v0 = *(const f32x4*)src, v1 = *(const f32x4*)(src + 4);
        fa[0] = (_Float16)v0.x; fa[1] = (_Float16)v0.y;
        fa[2] = (_Float16)v0.z; fa[3] = (_Float16)v0.w;
        fa[4] = (_Float16)v1.x; fa[5] = (_Float16)v1.y;
        fa[6] = (_Float16)v1.z; fa[7] = (_Float16)v1.w;
      }
      aA[m] = fa;
      const float* srb = whhRow + ks * 128 + m * 16 + klane;
      f32x4 w0 = *(const f32x4*)srb, w1 = *(const f32x4*)(srb + 4);
      h16x8 fb;
      fb[0] = (_Float16)w0.x; fb[1] = (_Float16)w0.y;
      fb[2] = (_Float16)w0.z; fb[3] = (_Float16)w0.w;
      fb[4] = (_Float16)w1.x; fb[5] = (_Float16)w1.y;
      fb[6] = (_Float16)w1.z; fb[7] = (_Float16)w1.w;
      aB[m] = fb;
    }
  }

  const int pb = tid >> 4, pcj = tid & 15;
  float bias4[4];
#pragma unroll
  for (int gi = 0; gi < 4; ++gi) {
    int grow = gi * H + j0 + pcj;
    bias4[gi] = bih[(size_t)l * G4 + grow] + bhh[(size_t)l * G4 + grow];
  }

  const int koff = (lane >> 5) * 8;
  // streaming-stage mapping: group = producer index, li = lane-in-group
  const int grp = tid >> 5, li = tid & 31;
  float creg = 0.f;

  for (int g = 0; g < GTOT; ++g) {
    const int t = g - SKEW * l;
    const bool active = (t >= 0) && (t < T);

    if (active) {
      // ========== PHASE A: stream-stage h_{l-1}(t) (slack edge) ==========
      if (l == 0) {
        const int row = tid >> 4, u = tid & 15;
        const float* xr = x + ((size_t)row * T + t) * D0 + u * 8;
        f32x4 v0 = *(const f32x4*)xr, v1 = *(const f32x4*)(xr + 4);
        h16x8 f;
        f[0] = (_Float16)v0.x; f[1] = (_Float16)v0.y;
        f[2] = (_Float16)v0.z; f[3] = (_Float16)v0.w;
        f[4] = (_Float16)v1.x; f[5] = (_Float16)v1.y;
        f[6] = (_Float16)v1.z; f[7] = (_Float16)v1.w;
        *(h16x8*)&h_sA[row * HSTRA + u * 8] = f;
      } else {
        // group grp: poll producer grp of layer l-1 (flag >= g-1), copy its
        // 16-col slice, rows li and li+32
        unsigned* fp = &flags[((l - 1) * 32 + grp) * FSTRIDE];
        while ((int)__hip_atomic_load(fp, __ATOMIC_RELAXED,
                                      __HIP_MEMORY_SCOPE_AGENT) < g - 1)
          __builtin_amdgcn_s_sleep(1);
        const unsigned short* rgA =
            ring + ((size_t)(l - 1) * T + t) * (B * H) + grp * 16;
        const unsigned short* s0 = rgA + (size_t)li * H;
        const unsigned short* s1 = rgA + (size_t)(li + 32) * H;
        f32x4 a0 = *(const f32x4*)s0, a1 = *(const f32x4*)(s0 + 8);
        f32x4 b0 = *(const f32x4*)s1, b1 = *(const f32x4*)(s1 + 8);
        *(f32x4*)&h_sA[li * HSTRA + grp * 16]            = a0;
        *(f32x4*)&h_sA[li * HSTRA + grp * 16 + 8]        = a1;
        *(f32x4*)&h_sA[(li + 32) * HSTRA + grp * 16]     = b0;
        *(f32x4*)&h_sA[(li + 32) * HSTRA + grp * 16 + 8] = b1;
      }
      __syncthreads();   // S1: h_sA staged

      f32x16 accv = {};
      {
        const unsigned short* ba =
            &h_sA[(bt * 32 + (lane & 31)) * HSTRA + ks * KA4 + koff];
#pragma unroll
        for (int m = 0; m < 8; ++m) {
          if (m < FA) {
            h16x8 b8 = *(const h16x8*)(ba + m * 16);
            accv = __builtin_amdgcn_mfma_f32_32x32x16_f16(aA[m], b8, accv, 0, 0, 0);
          }
        }
      }

      // ========== PHASE B: stream-stage h_l(t-1) (tight edge) ==========
      if (t > 0) {
        unsigned* fp = &flags[(l * 32 + grp) * FSTRIDE];
        while ((int)__hip_atomic_load(fp, __ATOMIC_RELAXED,
                                      __HIP_MEMORY_SCOPE_AGENT) < g)
          __builtin_amdgcn_s_sleep(1);
        const unsigned short* rgB =
            ring + ((size_t)l * T + (t - 1)) * (B * H) + grp * 16;
        const unsigned short* s0 = rgB + (size_t)li * H;
        const unsigned short* s1 = rgB + (size_t)(li + 32) * H;
        f32x4 a0 = *(const f32x4*)s0, a1 = *(const f32x4*)(s0 + 8);
        f32x4 b0 = *(const f32x4*)s1, b1 = *(const f32x4*)(s1 + 8);
        *(f32x4*)&h_sB[li * HSTRB + grp * 16]            = a0;
        *(f32x4*)&h_sB[li * HSTRB + grp * 16 + 8]        = a1;
        *(f32x4*)&h_sB[(li + 32) * HSTRB + grp * 16]     = b0;
        *(f32x4*)&h_sB[(li + 32) * HSTRB + grp * 16 + 8] = b1;
      }
      __syncthreads();   // S2: h_sB staged; also orders A-MFMA before g_par

      if (t > 0) {
        const unsigned short* bb =
            &h_sB[(bt * 32 + (lane & 31)) * HSTRB + ks * 128 + koff];
#pragma unroll
        for (int m = 0; m < 8; ++m) {
          h16x8 b8 = *(const h16x8*)(bb + m * 16);
          accv = __builtin_amdgcn_mfma_f32_32x32x16_f16(aB[m], b8, accv, 0, 0, 0);
        }
      }

      // ---- k-slice partials -> g_par (aliases h_sA) ----
      {
        float* gp = g_par +
            (size_t)((ks * 4 + (rt * 2 + bt)) * 32 + (lane & 31)) * GSTR +
            4 * (lane >> 5);
#pragma unroll
        for (int q = 0; q < 4; ++q) {
          f32x4 tv;
          tv.x = accv[4 * q];     tv.y = accv[4 * q + 1];
          tv.z = accv[4 * q + 2]; tv.w = accv[4 * q + 3];
          *(f32x4*)&gp[8 * q] = tv;
        }
      }
      __syncthreads();   // S3

      // ---- reduce + bias + pointwise + publish ----
      {
        float gt[4];
#pragma unroll
        for (int gi = 0; gi < 4; ++gi) {
          int rowL = gi * 16 + pcj;
          int tile = (rowL >> 5) * 2 + (pb >> 5);
          int rL   = rowL & 31;
          float s = bias4[gi];
#pragma unroll
          for (int ksi = 0; ksi < 4; ++ksi)
            s += g_par[(size_t)((ksi * 4 + tile) * 32 + (pb & 31)) * GSTR + rL];
          gt[gi] = s;
        }
        float iv = 1.f / (1.f + expf(-gt[0]));
        float fv = 1.f / (1.f + expf(-gt[1]));
        float gv = tanhf(gt[2]);
        float ov = 1.f / (1.f + expf(-gt[3]));
        creg = fv * creg + iv * gv;
        float hv = ov * tanhf(creg);
        _Float16 hf = (_Float16)hv;
        __hip_atomic_store(
            &ring[((size_t)l * T + t) * (B * H) + pb * H + j0 + pcj],
            __builtin_bit_cast(unsigned short, hf),
            __ATOMIC_RELAXED, __HIP_MEMORY_SCOPE_AGENT);
        if (l == NL - 1 && t == T - 1)
          h5[pb * H + j0 + pcj] = hv;
      }
      __syncthreads();   // S4: drain publish stores before flagging
    }

    if (tid == 0)
      __hip_atomic_store(&flags[blk * FSTRIDE], (unsigned)(g + 1),
                         __ATOMIC_RELAXED, __HIP_MEMORY_SCOPE_AGENT);
  }
}

// ===========================================================================
// Final FC on h_5(T-1) (f32 side buffer)
// ===========================================================================
__global__ void __launch_bounds__(640) fc_kernel(
    const float* __restrict__ h5, const float* __restrict__ w,
    const float* __restrict__ bias, float* __restrict__ out)
{
  int tid = threadIdx.x;
  if (tid >= 640) return;
  int b = tid / 10, o = tid - b * 10;
  const float* yr = h5 + (size_t)b * H;
  const float* wr = w + (size_t)o * H;
  float acc = bias[o];
  for (int k = 0; k < H; ++k) acc = fmaf(yr[k], wr[k], acc);
  out[b * 10 + o] = acc;
}

extern "C" void kernel_launch(void* const* d_in, const int* in_sizes, int n_in,
                              void* d_out, int out_size, void* d_ws,
                              size_t ws_size, hipStream_t stream)
{
  const float* x    = (const float*)d_in[0];
  const float* Wih0 = (const float*)d_in[1];
  const float* WihR = (const float*)d_in[2];
  const float* Whh  = (const float*)d_in[3];
  const float* bih  = (const float*)d_in[4];
  const float* bhh  = (const float*)d_in[5];
  const float* fcw  = (const float*)d_in[6];
  const float* fcb  = (const float*)d_in[7];
  float* out = (float*)d_out;

  // ws: [0,16K) flags; full-depth ring f16[6][T][B][H] (96 MB — size
  // empirically confirmed by r16's passing full-ring run); h5buf f32[B][H]
  unsigned* flags = (unsigned*)d_ws;
  unsigned short* ring = (unsigned short*)((char*)d_ws + 16384);
  const size_t ringFull = (size_t)NL * T * B * H * 2;
  float* h5buf = (float*)((char*)d_ws + 16384 + ringFull);

  hipMemsetAsync(d_ws, 0, 16384, stream);   // flags monotonic within a call

  lstm_pipe<<<NBLK_P, 1024, 0, stream>>>(x, Wih0, WihR, Whh, bih, bhh,
                                         ring, h5buf, flags);
  fc_kernel<<<1, 640, 0, stream>>>(h5buf, fcw, fcb, out);
}

// Round 19
// 1470.590 us; speedup vs baseline: 1.2618x; 1.2618x over previous
//
#include <hip/hip_runtime.h>

#define B 64
#define T 256
#define H 512
#define G4 2048
#define D0 128
#define NL 6
#define NBLK_P 192            // 6 layers x 32 col-groups
#define SKEW 2                // layer skew
#define GTOT (T + SKEW * (NL - 1))   // 266 global steps
#define FSTRIDE 16            // u32 stride between per-block flags (64B)
#define HSTRA 584             // h_sA row stride f16 (1168B == 16 mod 128)
#define HSTRB 520             // h_sB row stride f16 (1040B == 16 mod 128)
#define XSTR  136             // x_s  row stride f16 (272B  == 16 mod 128)
#define GSTR 36               // g_par row stride f32

typedef float f32x4 __attribute__((ext_vector_type(4)));
typedef float f32x16 __attribute__((ext_vector_type(16)));
typedef _Float16 h16x8 __attribute__((ext_vector_type(8)));

// ===========================================================================
// lstm_pipe v11 — r18 (cross-step A-prefetch) + the r18 NaN-race fix:
//  * r18 ERRATum: for l==0 the A-MFMAs (reading x from h_sA) ran in the same
//    sync region as the g_par writes (which ALIAS h_sA) — cross-wave race;
//    racing waves read f32-partial bytes as f16 fragments (NaN patterns) ->
//    MFMA NaN -> whole net NaN. Fix: l==0's x gets a DEDICATED x_s buffer
//    (17KB; LDS total 158720 B, still 1 block/CU). g_par keeps the h_sA
//    alias — safe for l>0 because A-MFMAs live in the shadow tail, two
//    syncs away from g_par writes.
//  * Rest identical to r18: at step-g entry h_{l-1}(t+1) is already
//    published (skew-2), so W1 waits (siblings >= g) AND (l-1 >= g); the
//    A(t+1) loads issue after W1 and drain under phase B; LDS-write +
//    8 A-MFMAs into a fresh accv run after publish+flag (shadow ~= flag
//    propagation delay). Serial loop: detect -> stage B -> MFMA B ->
//    reduce -> pointwise -> publish.
//  * Per-output MFMA order stays A-then-B -> bit-identical math; absmax
//    must be exactly 0.0001220703.
// ===========================================================================
__global__ void __launch_bounds__(1024, 2) lstm_pipe(
    const float* __restrict__ x,
    const float* __restrict__ Wih0, const float* __restrict__ WihR,
    const float* __restrict__ Whh,
    const float* __restrict__ bih, const float* __restrict__ bhh,
    unsigned short* __restrict__ ring, float* __restrict__ h5,
    unsigned* __restrict__ flags)
{
  __shared__ unsigned short h_sA[64 * HSTRA];   // 74752 B (g_par aliases)
  __shared__ unsigned short h_sB[64 * HSTRB];   // 66560 B
  __shared__ unsigned short x_s [64 * XSTR];    // 17408 B (l==0 x, NO alias)
  float* const g_par = (float*)h_sA;

  const int tid  = threadIdx.x;
  const int lane = tid & 63;
  const int wl   = __builtin_amdgcn_readfirstlane(tid >> 6);
  const int ks   = wl & 3;
  const int rt   = (wl >> 2) >> 1;
  const int bt   = (wl >> 2) & 1;
  const int blk  = (int)blockIdx.x;
  const int l    = blk >> 5;
  const int jb   = blk & 31;
  const int j0   = jb * 16;
  const int Kin  = (l == 0) ? D0 : H;
  const int KA4  = Kin >> 2;                // per-ks k width, phase A
  const int FA   = KA4 >> 4;                // phase-A frags: 2 or 8

  const float* WihA = (l == 0) ? Wih0 : (WihR + (size_t)(l - 1) * G4 * H);
  const float* WhhA = Whh + (size_t)l * G4 * H;

  // ---- one-time: W -> A-fragments in registers (f16; r12-verified map) ----
  h16x8 aA[8], aB[8];
  {
    const int ri   = rt * 32 + (lane & 31);
    const int grow = (ri >> 4) * H + j0 + (ri & 15);
    const float* wihRow = WihA + (size_t)grow * Kin;
    const float* whhRow = WhhA + (size_t)grow * H;
    const int klane = (lane >> 5) * 8;
#pragma unroll
    for (int m = 0; m < 8; ++m) {
      h16x8 fa = {};
      if (m < FA) {
        const float* src = wihRow + ks * KA4 + m * 16 + klane;
        f32x4 v0 = *(const f32x4*)src, v1 = *(const f32x4*)(src + 4);
        fa[0] = (_Float16)v0.x; fa[1] = (_Float16)v0.y;
        fa[2] = (_Float16)v0.z; fa[3] = (_Float16)v0.w;
        fa[4] = (_Float16)v1.x; fa[5] = (_Float16)v1.y;
        fa[6] = (_Float16)v1.z; fa[7] = (_Float16)v1.w;
      }
      aA[m] = fa;
      const float* srb = whhRow + ks * 128 + m * 16 + klane;
      f32x4 w0 = *(const f32x4*)srb, w1 = *(const f32x4*)(srb + 4);
      h16x8 fb;
      fb[0] = (_Float16)w0.x; fb[1] = (_Float16)w0.y;
      fb[2] = (_Float16)w0.z; fb[3] = (_Float16)w0.w;
      fb[4] = (_Float16)w1.x; fb[5] = (_Float16)w1.y;
      fb[6] = (_Float16)w1.z; fb[7] = (_Float16)w1.w;
      aB[m] = fb;
    }
  }

  const int pb = tid >> 4, pcj = tid & 15;
  float bias4[4];
#pragma unroll
  for (int gi = 0; gi < 4; ++gi) {
    int grow = gi * H + j0 + pcj;
    bias4[gi] = bih[(size_t)l * G4 + grow] + bhh[(size_t)l * G4 + grow];
  }

  const int koff = (lane >> 5) * 8;
  float creg = 0.f;
  f32x16 accv = {};    // carries A(t) contributions across steps (l>0)

  for (int g = 0; g < GTOT; ++g) {
    const int t  = g - SKEW * l;
    const int tN = t + 1;
    const bool act = (t >= 0) && (t < T);
    const bool pfA = (l > 0) && (tN >= 0) && (tN < T);  // prefetch next-A

    if (act || pfA) {
      // ---- W1: single wait. siblings >= g (B edge, line-safe monolithic)
      //      and l-1 >= g (next-step A data published at l-1's step g-1).
      {
        const bool ns = act && (t > 0);
        if ((ns || pfA) && tid < 32) {
          unsigned* fs = &flags[(l * 32 + tid) * FSTRIDE];
          unsigned* fu = pfA ? &flags[((l - 1) * 32 + tid) * FSTRIDE]
                             : (unsigned*)0;
          for (;;) {
            int ok = 1;
            if (ns) ok &= ((int)__hip_atomic_load(fs, __ATOMIC_RELAXED,
                                __HIP_MEMORY_SCOPE_AGENT) >= g);
            if (fu) ok &= ((int)__hip_atomic_load(fu, __ATOMIC_RELAXED,
                                __HIP_MEMORY_SCOPE_AGENT) >= g);
            if (ok) break;
            __builtin_amdgcn_s_sleep(1);
          }
        }
      }
      __syncthreads();   // W1

      // ---- issue A(tN) prefetch loads (drain under phase B) ----
      f32x4 pf[4];
      if (pfA) {
        const unsigned short* rgA =
            ring + ((size_t)(l - 1) * T + tN) * (B * H);
#pragma unroll
        for (int i = 0; i < 4; ++i) {
          int uu = tid + 1024 * i;
          pf[i] = *(const f32x4*)(rgA + (size_t)(uu >> 6) * H + (uu & 63) * 8);
        }
      }

      // ---- l==0: stage x(t) into DEDICATED x_s (no g_par alias) ----
      if (act && l == 0) {
        const int row = tid >> 4, u = tid & 15;
        const float* xr = x + ((size_t)row * T + t) * D0 + u * 8;
        f32x4 v0 = *(const f32x4*)xr, v1 = *(const f32x4*)(xr + 4);
        h16x8 f;
        f[0] = (_Float16)v0.x; f[1] = (_Float16)v0.y;
        f[2] = (_Float16)v0.z; f[3] = (_Float16)v0.w;
        f[4] = (_Float16)v1.x; f[5] = (_Float16)v1.y;
        f[6] = (_Float16)v1.z; f[7] = (_Float16)v1.w;
        *(h16x8*)&x_s[row * XSTR + u * 8] = f;
      }

      // ---- stage B: h_l(t-1) -> h_sB (plain cached, full-depth ring) ----
      if (act && t > 0) {
        const unsigned short* rgB =
            ring + ((size_t)l * T + (t - 1)) * (B * H);
        f32x4 rb[4];
#pragma unroll
        for (int i = 0; i < 4; ++i) {
          int uu = tid + 1024 * i;
          rb[i] = *(const f32x4*)(rgB + (size_t)(uu >> 6) * H + (uu & 63) * 8);
        }
#pragma unroll
        for (int i = 0; i < 4; ++i) {
          int uu = tid + 1024 * i;
          *(f32x4*)&h_sB[(uu >> 6) * HSTRB + (uu & 63) * 8] = rb[i];
        }
      }
      __syncthreads();   // W2: h_sB (and l==0's x_s) staged

      if (act) {
        if (l == 0) {
          accv = (f32x16){};   // l==0 computes A inline each step (from x_s)
          const unsigned short* ba =
              &x_s[(bt * 32 + (lane & 31)) * XSTR + ks * KA4 + koff];
#pragma unroll
          for (int m = 0; m < 2; ++m) {     // FA == 2 for l==0
            h16x8 b8 = *(const h16x8*)(ba + m * 16);
            accv = __builtin_amdgcn_mfma_f32_32x32x16_f16(aA[m], b8, accv, 0, 0, 0);
          }
        }
        if (t > 0) {
          const unsigned short* bb =
              &h_sB[(bt * 32 + (lane & 31)) * HSTRB + ks * 128 + koff];
#pragma unroll
          for (int m = 0; m < 8; ++m) {
            h16x8 b8 = *(const h16x8*)(bb + m * 16);
            accv = __builtin_amdgcn_mfma_f32_32x32x16_f16(aB[m], b8, accv, 0, 0, 0);
          }
        }
        // ---- k-slice partials -> g_par (aliases h_sA; safe: A-MFMAs for
        //      l>0 are in the shadow tail, l==0 reads x_s) ----
        float* gp = g_par +
            (size_t)((ks * 4 + (rt * 2 + bt)) * 32 + (lane & 31)) * GSTR +
            4 * (lane >> 5);
#pragma unroll
        for (int q = 0; q < 4; ++q) {
          f32x4 tv;
          tv.x = accv[4 * q];     tv.y = accv[4 * q + 1];
          tv.z = accv[4 * q + 2]; tv.w = accv[4 * q + 3];
          *(f32x4*)&gp[8 * q] = tv;
        }
      }
      __syncthreads();   // W3: g_par complete

      if (act) {
        float gt[4];
#pragma unroll
        for (int gi = 0; gi < 4; ++gi) {
          int rowL = gi * 16 + pcj;
          int tile = (rowL >> 5) * 2 + (pb >> 5);
          int rL   = rowL & 31;
          float s = bias4[gi];
#pragma unroll
          for (int ksi = 0; ksi < 4; ++ksi)
            s += g_par[(size_t)((ksi * 4 + tile) * 32 + (pb & 31)) * GSTR + rL];
          gt[gi] = s;
        }
        float iv = 1.f / (1.f + expf(-gt[0]));
        float fv = 1.f / (1.f + expf(-gt[1]));
        float gv = tanhf(gt[2]);
        float ov = 1.f / (1.f + expf(-gt[3]));
        creg = fv * creg + iv * gv;
        float hv = ov * tanhf(creg);
        _Float16 hf = (_Float16)hv;
        __hip_atomic_store(
            &ring[((size_t)l * T + t) * (B * H) + pb * H + j0 + pcj],
            __builtin_bit_cast(unsigned short, hf),
            __ATOMIC_RELAXED, __HIP_MEMORY_SCOPE_AGENT);
        if (l == NL - 1 && t == T - 1)
          h5[pb * H + j0 + pcj] = hv;
      }
      __syncthreads();   // W4: publish drained; g_par reads done -> h_sA free

      // ---- shadow tail part 1: prefetched A(tN) regs -> h_sA ----
      if (pfA) {
#pragma unroll
        for (int i = 0; i < 4; ++i) {
          int uu = tid + 1024 * i;
          *(f32x4*)&h_sA[(uu >> 6) * HSTRA + (uu & 63) * 8] = pf[i];
        }
      }
    }

    // ---- flag step-g completion (unconditional; after W4 when active) ----
    if (tid == 0)
      __hip_atomic_store(&flags[blk * FSTRIDE], (unsigned)(g + 1),
                         __ATOMIC_RELAXED, __HIP_MEMORY_SCOPE_AGENT);

    // ---- shadow tail part 2: A(tN) MFMAs into fresh accv (l>0) ----
    if (pfA) {
      __syncthreads();   // W5: h_sA written
      accv = (f32x16){};
      const unsigned short* ba =
          &h_sA[(bt * 32 + (lane & 31)) * HSTRA + ks * 128 + koff];
#pragma unroll
      for (int m = 0; m < 8; ++m) {
        h16x8 b8 = *(const h16x8*)(ba + m * 16);
        accv = __builtin_amdgcn_mfma_f32_32x32x16_f16(aA[m], b8, accv, 0, 0, 0);
      }
    }
  }
}

// ===========================================================================
// Final FC on h_5(T-1) (f32 side buffer)
// ===========================================================================
__global__ void __launch_bounds__(640) fc_kernel(
    const float* __restrict__ h5, const float* __restrict__ w,
    const float* __restrict__ bias, float* __restrict__ out)
{
  int tid = threadIdx.x;
  if (tid >= 640) return;
  int b = tid / 10, o = tid - b * 10;
  const float* yr = h5 + (size_t)b * H;
  const float* wr = w + (size_t)o * H;
  float acc = bias[o];
  for (int k = 0; k < H; ++k) acc = fmaf(yr[k], wr[k], acc);
  out[b * 10 + o] = acc;
}

extern "C" void kernel_launch(void* const* d_in, const int* in_sizes, int n_in,
                              void* d_out, int out_size, void* d_ws,
                              size_t ws_size, hipStream_t stream)
{
  const float* x    = (const float*)d_in[0];
  const float* Wih0 = (const float*)d_in[1];
  const float* WihR = (const float*)d_in[2];
  const float* Whh  = (const float*)d_in[3];
  const float* bih  = (const float*)d_in[4];
  const float* bhh  = (const float*)d_in[5];
  const float* fcw  = (const float*)d_in[6];
  const float* fcb  = (const float*)d_in[7];
  float* out = (float*)d_out;

  // ws: [0,16K) flags; full-depth ring f16[6][T][B][H] (96 MB, proven r16);
  //     h5buf f32[B][H]
  unsigned* flags = (unsigned*)d_ws;
  unsigned short* ring = (unsigned short*)((char*)d_ws + 16384);
  const size_t ringFull = (size_t)NL * T * B * H * 2;
  float* h5buf = (float*)((char*)d_ws + 16384 + ringFull);

  hipMemsetAsync(d_ws, 0, 16384, stream);   // flags monotonic within a call

  lstm_pipe<<<NBLK_P, 1024, 0, stream>>>(x, Wih0, WihR, Whh, bih, bhh,
                                         ring, h5buf, flags);
  fc_kernel<<<1, 640, 0, stream>>>(h5buf, fcw, fcb, out);
}